// Round 8
// baseline (247.672 us; speedup 1.0000x reference)
//
#include <hip/hip_runtime.h>
#include <hip/hip_bf16.h>

#define NWS 16
#define ZD 512
#define MM 100
#define NCOL 112             // padded col count (7 x 16)
#define QBYTES 28672         // quarter panel: 112 cols * 128 k * 2 B
#define PANEL_BYTES 114688   // 4 quarters
#define MSTRIDE 124          // floats per matrix in LDS (496 B, 16B-aligned, 2-way banks)
#define RSTRIDE 12           // floats per matrix row in LDS (48 B -> rows 16B-aligned)
#define EXP_NT 6

typedef __attribute__((ext_vector_type(8))) short bf16x8;
typedef __attribute__((ext_vector_type(4))) float f32x4;

static __device__ __forceinline__ unsigned short f2bf(float x) {
    union { __hip_bfloat16 h; unsigned short u; } cv;
    cv.h = __float2bfloat16(x);
    return cv.u;
}

// ---------------- Kernel 0: basis fp32 [w][k][ij] -> bf16 swizzled quarter panels
__global__ __launch_bounds__(256) void prep_basis(const float* __restrict__ basis,
                                                  unsigned char* __restrict__ Bt) {
    const int idx = blockIdx.x * 256 + threadIdx.x;   // 16*64*112 = 114688
    const int col  = idx % NCOL;
    const int rest = idx / NCOL;
    const int g    = rest & 63;        // k-group of 8
    const int w    = rest >> 6;

    bf16x8 pk;
    #pragma unroll
    for (int e = 0; e < 8; ++e) {
        const int k = g * 8 + e;
        const float v = (col < MM) ? basis[((size_t)(w * ZD + k)) * MM + col] : 0.f;
        pk[e] = (short)f2bf(v);
    }
    const int q  = g >> 4;             // quarter (128 k each)
    const int gl = g & 15;             // 16-B chunk within quarter-col
    const size_t off = (size_t)w * PANEL_BYTES + (size_t)q * QBYTES
                     + (size_t)col * 256 + (size_t)((gl * 16) ^ ((col & 7) << 4));
    *reinterpret_cast<bf16x8*>(Bt + off) = pk;
}

// ---------------- Fused kernel: einsum (bf16 MFMA) + in-block expm
// grid (16, 32), block 512. Per block: 128 batch rows of one w = 128 matrices.
// Phase 1: z @ basis -> acc (quarter-K pipeline, B panels dbuf in LDS).
// Phase 2: acc -> LDS (row-padded layout). Phase 3: expm, write lie_group.
__global__ __launch_bounds__(512, 4) void fused_kernel(const float* __restrict__ z,
                                                       const unsigned char* __restrict__ Btg,
                                                       float* __restrict__ out) {
    __shared__ __align__(16) float SMEMf[128 * MSTRIDE];   // 63488 B
    unsigned char* SMEM = (unsigned char*)SMEMf;

    const int w     = blockIdx.x;
    const int chunk = blockIdx.y;
    const int tid   = threadIdx.x;
    const int wave  = tid >> 6;
    const int lane  = tid & 63;
    const int l15   = lane & 15;
    const int k8    = lane >> 4;

    const int row = chunk * 128 + wave * 16 + l15;
    const float* zp = z + (size_t)row * (NWS * ZD) + (size_t)w * ZD + k8 * 8;
    const unsigned char* bt = Btg + (size_t)w * PANEL_BYTES;

    int bbase[7];
    #pragma unroll
    for (int nf = 0; nf < 7; ++nf) bbase[nf] = (nf * 16 + l15) * 256;
    const int bswz = (l15 & 7) << 4;

    float4 zf[8];

    #define STAGE_Q(t, buf)                                                              \
        do {                                                                             \
            const unsigned char* gq = bt + (t) * QBYTES;                                 \
            unsigned char* ls = SMEM + (buf) * QBYTES;                                   \
            _Pragma("unroll")                                                            \
            for (int r = 0; r < 3; ++r) {                                                \
                __builtin_amdgcn_global_load_lds(                                        \
                    (const __attribute__((address_space(1))) unsigned int*)(gq + (r * 512 + tid) * 16), \
                    (__attribute__((address_space(3))) unsigned int*)(ls + (r * 512 + tid) * 16),       \
                    16, 0, 0);                                                           \
            }                                                                            \
            if (tid < 256) {                                                             \
                __builtin_amdgcn_global_load_lds(                                        \
                    (const __attribute__((address_space(1))) unsigned int*)(gq + (1536 + tid) * 16),    \
                    (__attribute__((address_space(3))) unsigned int*)(ls + (1536 + tid) * 16),          \
                    16, 0, 0);                                                           \
            }                                                                            \
        } while (0)

    #define ZLOAD_Q(t)                                                                   \
        do {                                                                             \
            _Pragma("unroll")                                                            \
            for (int j = 0; j < 4; ++j) {                                                \
                zf[2 * j]     = *reinterpret_cast<const float4*>(zp + ((t) * 4 + j) * 32);      \
                zf[2 * j + 1] = *reinterpret_cast<const float4*>(zp + ((t) * 4 + j) * 32 + 4);  \
            }                                                                            \
        } while (0)

    f32x4 acc[7];
    #pragma unroll
    for (int nf = 0; nf < 7; ++nf) acc[nf] = (f32x4){0.f, 0.f, 0.f, 0.f};

    STAGE_Q(0, 0);
    ZLOAD_Q(0);
    __syncthreads();

    #pragma unroll
    for (int t = 0; t < 4; ++t) {
        bf16x8 zb[4];
        #pragma unroll
        for (int j = 0; j < 4; ++j) {
            zb[j][0] = (short)f2bf(zf[2 * j].x);
            zb[j][1] = (short)f2bf(zf[2 * j].y);
            zb[j][2] = (short)f2bf(zf[2 * j].z);
            zb[j][3] = (short)f2bf(zf[2 * j].w);
            zb[j][4] = (short)f2bf(zf[2 * j + 1].x);
            zb[j][5] = (short)f2bf(zf[2 * j + 1].y);
            zb[j][6] = (short)f2bf(zf[2 * j + 1].z);
            zb[j][7] = (short)f2bf(zf[2 * j + 1].w);
        }
        if (t < 3) {
            STAGE_Q(t + 1, (t + 1) & 1);
            ZLOAD_Q(t + 1);
        }
        #pragma unroll
        for (int s = 0; s < 4; ++s) {
            const int klb = (s * 64 + k8 * 16) ^ bswz;
            const unsigned char* bq = SMEM + (t & 1) * QBYTES;
            #pragma unroll
            for (int nf = 0; nf < 7; ++nf) {
                const bf16x8 bfr = *reinterpret_cast<const bf16x8*>(bq + bbase[nf] + klb);
                acc[nf] = __builtin_amdgcn_mfma_f32_16x16x32_bf16(zb[s], bfr, acc[nf], 0, 0, 0);
            }
        }
        __syncthreads();   // t<3: drains next STAGE+z, protects flip; t=3: protects C overlay
    }
    #undef STAGE_Q
    #undef ZLOAD_Q

    // ---- Phase 2: acc -> LDS matrices (row-padded). element (i,j) at m*124 + i*12 + j
    {
        const int mbase = wave * 16 + k8 * 4;
        #pragma unroll
        for (int nf = 0; nf < 7; ++nf) {
            const int col = nf * 16 + l15;
            if (col < MM) {
                const int ci = col / 10;
                const int cj = col - ci * 10;
                #pragma unroll
                for (int r = 0; r < 4; ++r)
                    SMEMf[(mbase + r) * MSTRIDE + ci * RSTRIDE + cj] = acc[nf][r];
            }
        }
    }
    __syncthreads();

    // ---- Phase 3: expm. 128 matrices x 4 threads; thread owns cols {c, c+4, c+8}.
    {
        const int mat = tid >> 2;
        const int c   = tid & 3;
        const float* A = SMEMf + mat * MSTRIDE;
        const int j0 = c, j1 = c + 4, j2 = c + 8;       // j2 >= 10 for c >= 2 (dummy)
        const int j2c = (j2 < 10) ? j2 : 9;

        float p0[10], p1[10], p2[10];
        #pragma unroll
        for (int i = 0; i < 10; ++i) {
            p0[i] = A[i * RSTRIDE + j0]  * (1.f / EXP_NT) + ((i == j0) ? 1.f : 0.f);
            p1[i] = A[i * RSTRIDE + j1]  * (1.f / EXP_NT) + ((i == j1) ? 1.f : 0.f);
            p2[i] = A[i * RSTRIDE + j2c] * (1.f / EXP_NT) + ((i == j2) ? 1.f : 0.f);
        }

        #pragma unroll
        for (int k = EXP_NT - 1; k >= 1; --k) {
            float n0[10], n1[10], n2[10];
            #pragma unroll
            for (int i = 0; i < 10; ++i) {
                float ar[10];
                const float4 v0 = *reinterpret_cast<const float4*>(A + i * RSTRIDE);
                const float4 v1 = *reinterpret_cast<const float4*>(A + i * RSTRIDE + 4);
                const float2 v2 = *reinterpret_cast<const float2*>(A + i * RSTRIDE + 8);
                ar[0] = v0.x; ar[1] = v0.y; ar[2] = v0.z; ar[3] = v0.w;
                ar[4] = v1.x; ar[5] = v1.y; ar[6] = v1.z; ar[7] = v1.w;
                ar[8] = v2.x; ar[9] = v2.y;
                float s0 = 0.f, s1 = 0.f, s2 = 0.f;
                #pragma unroll
                for (int kk = 0; kk < 10; ++kk) {
                    s0 = fmaf(ar[kk], p0[kk], s0);
                    s1 = fmaf(ar[kk], p1[kk], s1);
                    s2 = fmaf(ar[kk], p2[kk], s2);
                }
                n0[i] = s0; n1[i] = s1; n2[i] = s2;
            }
            const float invk = 1.f / (float)k;
            #pragma unroll
            for (int i = 0; i < 10; ++i) {
                p0[i] = n0[i] * invk + ((i == j0) ? 1.f : 0.f);
                p1[i] = n1[i] * invk + ((i == j1) ? 1.f : 0.f);
                p2[i] = n2[i] * invk + ((i == j2) ? 1.f : 0.f);
            }
        }

        const int gb = chunk * 128 + mat;
        float* op = out + ((size_t)gb * NWS + w) * MM;
        #pragma unroll
        for (int i = 0; i < 10; ++i) {
            op[i * 10 + j0] = p0[i];
            op[i * 10 + j1] = p1[i];
            if (j2 < 10) op[i * 10 + j2] = p2[i];
        }
    }
}

extern "C" void kernel_launch(void* const* d_in, const int* in_sizes, int n_in,
                              void* d_out, int out_size, void* d_ws, size_t ws_size,
                              hipStream_t stream) {
    const float* z     = (const float*)d_in[0];   // [4096,16,512]
    const float* basis = (const float*)d_in[1];   // [16,512,10,10]
    float* out = (float*)d_out;                   // [4096,16,10,10]
    unsigned char* Bt = (unsigned char*)d_ws;     // 16 * 114688 B = 1.83 MB

    prep_basis<<<(NWS * 64 * NCOL) / 256, 256, 0, stream>>>(basis, Bt);

    dim3 grid(NWS, 32);
    fused_kernel<<<grid, 512, 0, stream>>>(z, Bt, out);
}

// Round 9
// 211.163 us; speedup vs baseline: 1.1729x; 1.1729x over previous
//
#include <hip/hip_runtime.h>
#include <hip/hip_bf16.h>

#define NWS 16
#define ZD 512
#define MM 100
#define NCOL 112             // padded col count (7 x 16)
#define QBYTES 28672         // quarter panel: 112 cols * 128 k * 2 B
#define PANEL_BYTES 114688   // 4 quarters
#define MSTRIDE 124          // floats per matrix in LDS (496 B, 16B-aligned)
#define RSTRIDE 12           // floats per matrix row in LDS (48 B -> rows 16B-aligned)
#define EXP_NT 6

typedef __attribute__((ext_vector_type(8))) short bf16x8;
typedef __attribute__((ext_vector_type(4))) float f32x4;

static __device__ __forceinline__ unsigned short f2bf(float x) {
    union { __hip_bfloat16 h; unsigned short u; } cv;
    cv.h = __float2bfloat16(x);
    return cv.u;
}

// ---------------- Kernel 0: basis fp32 [w][k][ij] -> bf16 swizzled quarter panels
__global__ __launch_bounds__(256) void prep_basis(const float* __restrict__ basis,
                                                  unsigned char* __restrict__ Bt) {
    const int idx = blockIdx.x * 256 + threadIdx.x;   // 16*64*112 = 114688
    const int col  = idx % NCOL;
    const int rest = idx / NCOL;
    const int g    = rest & 63;        // k-group of 8
    const int w    = rest >> 6;

    bf16x8 pk;
    #pragma unroll
    for (int e = 0; e < 8; ++e) {
        const int k = g * 8 + e;
        const float v = (col < MM) ? basis[((size_t)(w * ZD + k)) * MM + col] : 0.f;
        pk[e] = (short)f2bf(v);
    }
    const int q  = g >> 4;             // quarter (128 k each)
    const int gl = g & 15;             // 16-B chunk within quarter-col
    const size_t off = (size_t)w * PANEL_BYTES + (size_t)q * QBYTES
                     + (size_t)col * 256 + (size_t)((gl * 16) ^ ((col & 7) << 4));
    *reinterpret_cast<bf16x8*>(Bt + off) = pk;
}

// ---------------- Fused kernel: einsum (bf16 MFMA) + in-block expm
// grid (16, 32), block 512. Per block: 128 batch rows of one w = 128 matrices.
// Phase 3 register budget kept <= ~55 arch VGPRs (R8 spilled at 70 due to
// arch/accum register-file split under __launch_bounds__(512,4)).
__global__ __launch_bounds__(512, 4) void fused_kernel(const float* __restrict__ z,
                                                       const unsigned char* __restrict__ Btg,
                                                       float* __restrict__ out) {
    __shared__ __align__(16) float SMEMf[128 * MSTRIDE];   // 63488 B
    unsigned char* SMEM = (unsigned char*)SMEMf;

    const int w     = blockIdx.x;
    const int chunk = blockIdx.y;
    const int tid   = threadIdx.x;
    const int wave  = tid >> 6;
    const int lane  = tid & 63;
    const int l15   = lane & 15;
    const int k8    = lane >> 4;

    const int row = chunk * 128 + wave * 16 + l15;
    const float* zp = z + (size_t)row * (NWS * ZD) + (size_t)w * ZD + k8 * 8;
    const unsigned char* bt = Btg + (size_t)w * PANEL_BYTES;

    int bbase[7];
    #pragma unroll
    for (int nf = 0; nf < 7; ++nf) bbase[nf] = (nf * 16 + l15) * 256;
    const int bswz = (l15 & 7) << 4;

    float4 zf[8];

    #define STAGE_Q(t, buf)                                                              \
        do {                                                                             \
            const unsigned char* gq = bt + (t) * QBYTES;                                 \
            unsigned char* ls = SMEM + (buf) * QBYTES;                                   \
            _Pragma("unroll")                                                            \
            for (int r = 0; r < 3; ++r) {                                                \
                __builtin_amdgcn_global_load_lds(                                        \
                    (const __attribute__((address_space(1))) unsigned int*)(gq + (r * 512 + tid) * 16), \
                    (__attribute__((address_space(3))) unsigned int*)(ls + (r * 512 + tid) * 16),       \
                    16, 0, 0);                                                           \
            }                                                                            \
            if (tid < 256) {                                                             \
                __builtin_amdgcn_global_load_lds(                                        \
                    (const __attribute__((address_space(1))) unsigned int*)(gq + (1536 + tid) * 16),    \
                    (__attribute__((address_space(3))) unsigned int*)(ls + (1536 + tid) * 16),          \
                    16, 0, 0);                                                           \
            }                                                                            \
        } while (0)

    #define ZLOAD_Q(t)                                                                   \
        do {                                                                             \
            _Pragma("unroll")                                                            \
            for (int j = 0; j < 4; ++j) {                                                \
                zf[2 * j]     = *reinterpret_cast<const float4*>(zp + ((t) * 4 + j) * 32);      \
                zf[2 * j + 1] = *reinterpret_cast<const float4*>(zp + ((t) * 4 + j) * 32 + 4);  \
            }                                                                            \
        } while (0)

    f32x4 acc[7];
    #pragma unroll
    for (int nf = 0; nf < 7; ++nf) acc[nf] = (f32x4){0.f, 0.f, 0.f, 0.f};

    STAGE_Q(0, 0);
    ZLOAD_Q(0);
    __syncthreads();

    #pragma unroll
    for (int t = 0; t < 4; ++t) {
        bf16x8 zb[4];
        #pragma unroll
        for (int j = 0; j < 4; ++j) {
            zb[j][0] = (short)f2bf(zf[2 * j].x);
            zb[j][1] = (short)f2bf(zf[2 * j].y);
            zb[j][2] = (short)f2bf(zf[2 * j].z);
            zb[j][3] = (short)f2bf(zf[2 * j].w);
            zb[j][4] = (short)f2bf(zf[2 * j + 1].x);
            zb[j][5] = (short)f2bf(zf[2 * j + 1].y);
            zb[j][6] = (short)f2bf(zf[2 * j + 1].z);
            zb[j][7] = (short)f2bf(zf[2 * j + 1].w);
        }
        if (t < 3) {
            STAGE_Q(t + 1, (t + 1) & 1);
            ZLOAD_Q(t + 1);
        }
        #pragma unroll
        for (int s = 0; s < 4; ++s) {
            const int klb = (s * 64 + k8 * 16) ^ bswz;
            const unsigned char* bq = SMEM + (t & 1) * QBYTES;
            #pragma unroll
            for (int nf = 0; nf < 7; ++nf) {
                const bf16x8 bfr = *reinterpret_cast<const bf16x8*>(bq + bbase[nf] + klb);
                acc[nf] = __builtin_amdgcn_mfma_f32_16x16x32_bf16(zb[s], bfr, acc[nf], 0, 0, 0);
            }
        }
        __syncthreads();   // t<3: drains next STAGE+z, protects flip; t=3: protects C overlay
    }
    #undef STAGE_Q
    #undef ZLOAD_Q

    // ---- Phase 2: acc -> LDS matrices (row-padded). element (i,j) at m*124 + i*12 + j
    {
        const int mbase = wave * 16 + k8 * 4;
        #pragma unroll
        for (int nf = 0; nf < 7; ++nf) {
            const int col = nf * 16 + l15;
            if (col < MM) {
                const int ci = col / 10;
                const int cj = col - ci * 10;
                #pragma unroll
                for (int r = 0; r < 4; ++r)
                    SMEMf[(mbase + r) * MSTRIDE + ci * RSTRIDE + cj] = acc[nf][r];
            }
        }
    }
    __syncthreads();

    // ---- Phase 3, Pass A: 512 threads = 128 matrices x 4 threads x 2 cols (cols 0..7)
    {
        const int mat = tid >> 2;
        const int c   = tid & 3;
        const int j0  = 2 * c, j1 = 2 * c + 1;
        const float* A = SMEMf + mat * MSTRIDE;

        float p0[10], p1[10];
        #pragma unroll
        for (int i = 0; i < 10; ++i) {
            p0[i] = A[i * RSTRIDE + j0] * (1.f / EXP_NT) + ((i == j0) ? 1.f : 0.f);
            p1[i] = A[i * RSTRIDE + j1] * (1.f / EXP_NT) + ((i == j1) ? 1.f : 0.f);
        }
        #pragma unroll
        for (int k = EXP_NT - 1; k >= 1; --k) {
            float n0[10], n1[10];
            #pragma unroll
            for (int i = 0; i < 10; ++i) {
                const float4 v0 = *reinterpret_cast<const float4*>(A + i * RSTRIDE);
                const float4 v1 = *reinterpret_cast<const float4*>(A + i * RSTRIDE + 4);
                const float2 v2 = *reinterpret_cast<const float2*>(A + i * RSTRIDE + 8);
                float s0, s1;
                s0 = v0.x * p0[0]; s1 = v0.x * p1[0];
                s0 = fmaf(v0.y, p0[1], s0); s1 = fmaf(v0.y, p1[1], s1);
                s0 = fmaf(v0.z, p0[2], s0); s1 = fmaf(v0.z, p1[2], s1);
                s0 = fmaf(v0.w, p0[3], s0); s1 = fmaf(v0.w, p1[3], s1);
                s0 = fmaf(v1.x, p0[4], s0); s1 = fmaf(v1.x, p1[4], s1);
                s0 = fmaf(v1.y, p0[5], s0); s1 = fmaf(v1.y, p1[5], s1);
                s0 = fmaf(v1.z, p0[6], s0); s1 = fmaf(v1.z, p1[6], s1);
                s0 = fmaf(v1.w, p0[7], s0); s1 = fmaf(v1.w, p1[7], s1);
                s0 = fmaf(v2.x, p0[8], s0); s1 = fmaf(v2.x, p1[8], s1);
                s0 = fmaf(v2.y, p0[9], s0); s1 = fmaf(v2.y, p1[9], s1);
                n0[i] = s0; n1[i] = s1;
            }
            const float invk = 1.f / (float)k;
            #pragma unroll
            for (int i = 0; i < 10; ++i) {
                p0[i] = n0[i] * invk + ((i == j0) ? 1.f : 0.f);
                p1[i] = n1[i] * invk + ((i == j1) ? 1.f : 0.f);
            }
        }
        const int gb = chunk * 128 + mat;
        float* op = out + ((size_t)gb * NWS + w) * MM;
        #pragma unroll
        for (int i = 0; i < 10; ++i)
            *reinterpret_cast<float2*>(op + i * 10 + j0) = make_float2(p0[i], p1[i]);
    }

    // ---- Phase 3, Pass B: 256 threads = 128 matrices x 2 threads x 1 col (cols 8..9)
    if (tid < 256) {
        const int mat = tid >> 1;
        const int j   = 8 + (tid & 1);
        const float* A = SMEMf + mat * MSTRIDE;

        float p[10];
        #pragma unroll
        for (int i = 0; i < 10; ++i)
            p[i] = A[i * RSTRIDE + j] * (1.f / EXP_NT) + ((i == j) ? 1.f : 0.f);

        #pragma unroll
        for (int k = EXP_NT - 1; k >= 1; --k) {
            float n[10];
            #pragma unroll
            for (int i = 0; i < 10; ++i) {
                const float4 v0 = *reinterpret_cast<const float4*>(A + i * RSTRIDE);
                const float4 v1 = *reinterpret_cast<const float4*>(A + i * RSTRIDE + 4);
                const float2 v2 = *reinterpret_cast<const float2*>(A + i * RSTRIDE + 8);
                float s;
                s = v0.x * p[0];
                s = fmaf(v0.y, p[1], s);
                s = fmaf(v0.z, p[2], s);
                s = fmaf(v0.w, p[3], s);
                s = fmaf(v1.x, p[4], s);
                s = fmaf(v1.y, p[5], s);
                s = fmaf(v1.z, p[6], s);
                s = fmaf(v1.w, p[7], s);
                s = fmaf(v2.x, p[8], s);
                s = fmaf(v2.y, p[9], s);
                n[i] = s;
            }
            const float invk = 1.f / (float)k;
            #pragma unroll
            for (int i = 0; i < 10; ++i)
                p[i] = n[i] * invk + ((i == j) ? 1.f : 0.f);
        }
        const int gb = chunk * 128 + mat;
        float* op = out + ((size_t)gb * NWS + w) * MM;
        #pragma unroll
        for (int i = 0; i < 10; ++i)
            op[i * 10 + j] = p[i];
    }
}

extern "C" void kernel_launch(void* const* d_in, const int* in_sizes, int n_in,
                              void* d_out, int out_size, void* d_ws, size_t ws_size,
                              hipStream_t stream) {
    const float* z     = (const float*)d_in[0];   // [4096,16,512]
    const float* basis = (const float*)d_in[1];   // [16,512,10,10]
    float* out = (float*)d_out;                   // [4096,16,10,10]
    unsigned char* Bt = (unsigned char*)d_ws;     // 16 * 114688 B = 1.83 MB

    prep_basis<<<(NWS * 64 * NCOL) / 256, 256, 0, stream>>>(basis, Bt);

    dim3 grid(NWS, 32);
    fused_kernel<<<grid, 512, 0, stream>>>(z, Bt, out);
}

// Round 10
// 57.089 us; speedup vs baseline: 4.3383x; 3.6988x over previous
//
#include <hip/hip_runtime.h>
#include <hip/hip_bf16.h>

#define NWS 16
#define ZD 512
#define MM 100
#define NCOL 112             // padded col count (7 x 16)
#define EBYTES 14336         // eighth panel: 112 cols * 64 k * 2 B
#define PANEL_BYTES 114688   // 8 eighths
#define EXP_NT 6

typedef __attribute__((ext_vector_type(8))) short bf16x8;
typedef __attribute__((ext_vector_type(4))) float f32x4;

static __device__ __forceinline__ unsigned short f2bf(float x) {
    union { __hip_bfloat16 h; unsigned short u; } cv;
    cv.h = __float2bfloat16(x);
    return cv.u;
}

// ---------------- Kernel 0: basis fp32 [w][k][ij] -> bf16 swizzled eighth panels
// Bt[w][e][col][128B] with byte swizzle ((col&7)<<4) XOR'd into the 128-B k-range.
__global__ __launch_bounds__(256) void prep_basis(const float* __restrict__ basis,
                                                  unsigned char* __restrict__ Bt) {
    const int idx = blockIdx.x * 256 + threadIdx.x;   // 16*64*112 = 114688
    const int col  = idx % NCOL;
    const int rest = idx / NCOL;
    const int g    = rest & 63;        // k-group of 8
    const int w    = rest >> 6;

    bf16x8 pk;
    #pragma unroll
    for (int e = 0; e < 8; ++e) {
        const int k = g * 8 + e;
        const float v = (col < MM) ? basis[((size_t)(w * ZD + k)) * MM + col] : 0.f;
        pk[e] = (short)f2bf(v);
    }
    const int e8  = g >> 3;            // eighth (64 k each)
    const int gl8 = g & 7;             // 16-B chunk within eighth-col
    const size_t off = (size_t)w * PANEL_BYTES + (size_t)e8 * EBYTES
                     + (size_t)col * 128 + (size_t)((gl8 * 16) ^ ((col & 7) << 4));
    *reinterpret_cast<bf16x8*>(Bt + off) = pk;
}

// ---------------- Kernel A: lie_alg = z @ basis via bf16 MFMA
// grid (64, 16): blockIdx.x = batch-chunk (fast dim -> same-chunk blocks share XCD/L2),
// blockIdx.y = w. 256 threads (4 waves x 16 rows = 64 rows/block).
// K split into 8 eighths; eighth-panels double-buffered (2 x 14336 B LDS).
__global__ __launch_bounds__(256, 4) void einsum_mfma(const float* __restrict__ z,
                                                      const unsigned char* __restrict__ Btg,
                                                      float* __restrict__ out) {
    __shared__ __align__(16) unsigned char Bs[2][EBYTES];
    const int chunk = blockIdx.x;      // 0..63 (fast -> chunk%8 picks XCD)
    const int w     = blockIdx.y;
    const int tid   = threadIdx.x;
    const int wave  = tid >> 6;
    const int lane  = tid & 63;
    const int l15   = lane & 15;
    const int k8    = lane >> 4;

    const int row = chunk * 64 + wave * 16 + l15;
    const float* zp = z + (size_t)row * (NWS * ZD) + (size_t)w * ZD + k8 * 8;
    const unsigned char* bt = Btg + (size_t)w * PANEL_BYTES;

    int bbase[7];
    #pragma unroll
    for (int nf = 0; nf < 7; ++nf) bbase[nf] = (nf * 16 + l15) * 128;
    const int bswz = (l15 & 7) << 4;

    float4 zf[4];                      // current eighth's z (2 K-steps x 8 floats)

    #define STAGE_E(t, buf)                                                              \
        do {                                                                             \
            const unsigned char* gq = bt + (t) * EBYTES;                                 \
            _Pragma("unroll")                                                            \
            for (int r = 0; r < 3; ++r) {                                                \
                __builtin_amdgcn_global_load_lds(                                        \
                    (const __attribute__((address_space(1))) unsigned int*)(gq + (r * 256 + tid) * 16), \
                    (__attribute__((address_space(3))) unsigned int*)(&Bs[buf][(r * 256 + tid) * 16]),  \
                    16, 0, 0);                                                           \
            }                                                                            \
            if (tid < 128) {                                                             \
                __builtin_amdgcn_global_load_lds(                                        \
                    (const __attribute__((address_space(1))) unsigned int*)(gq + (768 + tid) * 16),     \
                    (__attribute__((address_space(3))) unsigned int*)(&Bs[buf][(768 + tid) * 16]),      \
                    16, 0, 0);                                                           \
            }                                                                            \
        } while (0)

    #define ZLOAD_E(t)                                                                   \
        do {                                                                             \
            _Pragma("unroll")                                                            \
            for (int j = 0; j < 2; ++j) {                                                \
                zf[2 * j]     = *reinterpret_cast<const float4*>(zp + ((t) * 2 + j) * 32);      \
                zf[2 * j + 1] = *reinterpret_cast<const float4*>(zp + ((t) * 2 + j) * 32 + 4);  \
            }                                                                            \
        } while (0)

    f32x4 acc[7];
    #pragma unroll
    for (int nf = 0; nf < 7; ++nf) acc[nf] = (f32x4){0.f, 0.f, 0.f, 0.f};

    STAGE_E(0, 0);
    ZLOAD_E(0);
    __syncthreads();

    #pragma unroll
    for (int t = 0; t < 8; ++t) {
        // convert current eighth's z (resident in regs)
        bf16x8 zb[2];
        #pragma unroll
        for (int j = 0; j < 2; ++j) {
            zb[j][0] = (short)f2bf(zf[2 * j].x);
            zb[j][1] = (short)f2bf(zf[2 * j].y);
            zb[j][2] = (short)f2bf(zf[2 * j].z);
            zb[j][3] = (short)f2bf(zf[2 * j].w);
            zb[j][4] = (short)f2bf(zf[2 * j + 1].x);
            zb[j][5] = (short)f2bf(zf[2 * j + 1].y);
            zb[j][6] = (short)f2bf(zf[2 * j + 1].z);
            zb[j][7] = (short)f2bf(zf[2 * j + 1].w);
        }
        // issue next eighth's staging + z loads (in flight during compute)
        if (t < 7) {
            STAGE_E(t + 1, (t + 1) & 1);
            ZLOAD_E(t + 1);
        }
        // compute current eighth: 2 K-steps x 7 MFMA, pure LDS + MFMA
        #pragma unroll
        for (int s = 0; s < 2; ++s) {
            const int klb = (s * 64 + k8 * 16) ^ bswz;
            #pragma unroll
            for (int nf = 0; nf < 7; ++nf) {
                const bf16x8 bfr = *reinterpret_cast<const bf16x8*>(&Bs[t & 1][bbase[nf] + klb]);
                acc[nf] = __builtin_amdgcn_mfma_f32_16x16x32_bf16(zb[s], bfr, acc[nf], 0, 0, 0);
            }
        }
        if (t < 7) __syncthreads();    // drains next STAGE+z; protects buffer flip
    }
    #undef STAGE_E
    #undef ZLOAD_E

    // C layout: col = lane&15, row = (lane>>4)*4 + r  (verified R2/R3)
    const int rowbase = chunk * 64 + wave * 16 + k8 * 4;
    #pragma unroll
    for (int nf = 0; nf < 7; ++nf) {
        const int col = nf * 16 + l15;
        if (col < MM) {
            #pragma unroll
            for (int r = 0; r < 4; ++r)
                out[((size_t)(rowbase + r) * NWS + w) * MM + col] = acc[nf][r];
        }
    }
}

// ---------------- Kernel B: in-place expm of 10x10 matrices (proven R4 design)
// block 320 = 64 matrices x 5 threads; thread owns 2 columns; A in registers
// (STATIC indexing only — init columns read from LDS to avoid scratch demotion).
__global__ __launch_bounds__(320, 2) void expm_kernel(float* __restrict__ out) {
    __shared__ float As[64 * 100];
    const int t = threadIdx.x;
    const size_t base = (size_t)blockIdx.x * 6400;

    #pragma unroll
    for (int q = 0; q < 5; ++q) {
        const int idx = (q * 320 + t) * 4;
        *reinterpret_cast<float4*>(&As[idx]) =
            *reinterpret_cast<const float4*>(out + base + idx);
    }
    __syncthreads();

    const int m  = t / 5;
    const int c  = t - m * 5;
    const int j0 = 2 * c, j1 = j0 + 1;
    const float* A = &As[m * 100];

    float a[100];                          // statically indexed ONLY -> registers
    #pragma unroll
    for (int q = 0; q < 25; ++q) {
        const float4 v = *reinterpret_cast<const float4*>(A + q * 4);
        a[q * 4 + 0] = v.x; a[q * 4 + 1] = v.y;
        a[q * 4 + 2] = v.z; a[q * 4 + 3] = v.w;
    }

    float p0[10], p1[10];
    #pragma unroll
    for (int i = 0; i < 10; ++i) {
        p0[i] = A[i * 10 + j0] * (1.f / EXP_NT) + ((i == j0) ? 1.f : 0.f);
        p1[i] = A[i * 10 + j1] * (1.f / EXP_NT) + ((i == j1) ? 1.f : 0.f);
    }

    #pragma unroll
    for (int k = EXP_NT - 1; k >= 1; --k) {
        float n0[10], n1[10];
        #pragma unroll
        for (int i = 0; i < 10; ++i) { n0[i] = 0.f; n1[i] = 0.f; }
        #pragma unroll
        for (int kk = 0; kk < 10; ++kk) {
            const float q0 = p0[kk], q1 = p1[kk];
            #pragma unroll
            for (int i = 0; i < 10; ++i) {
                n0[i] = fmaf(a[i * 10 + kk], q0, n0[i]);
                n1[i] = fmaf(a[i * 10 + kk], q1, n1[i]);
            }
        }
        const float invk = 1.f / (float)k;
        #pragma unroll
        for (int i = 0; i < 10; ++i) {
            p0[i] = n0[i] * invk + ((i == j0) ? 1.f : 0.f);
            p1[i] = n1[i] * invk + ((i == j1) ? 1.f : 0.f);
        }
    }

    #pragma unroll
    for (int i = 0; i < 10; ++i)
        *reinterpret_cast<float2*>(out + base + m * 100 + i * 10 + j0) =
            make_float2(p0[i], p1[i]);
}

extern "C" void kernel_launch(void* const* d_in, const int* in_sizes, int n_in,
                              void* d_out, int out_size, void* d_ws, size_t ws_size,
                              hipStream_t stream) {
    const float* z     = (const float*)d_in[0];   // [4096,16,512]
    const float* basis = (const float*)d_in[1];   // [16,512,10,10]
    float* out = (float*)d_out;                   // [4096,16,10,10]
    unsigned char* Bt = (unsigned char*)d_ws;     // 16 * 114688 B = 1.83 MB

    prep_basis<<<(NWS * 64 * NCOL) / 256, 256, 0, stream>>>(basis, Bt);

    dim3 gridA(64, NWS);                          // chunk-major: chunk%8 -> XCD
    einsum_mfma<<<gridA, 256, 0, stream>>>(z, Bt, out);

    expm_kernel<<<(4096 * NWS) / 64, 320, 0, stream>>>(out);
}